// Round 9
// baseline (1202.453 us; speedup 1.0000x reference)
//
#include <hip/hip_runtime.h>
#include <math.h>

// TransformerBlock1: b=4, DIM=192, h=256, w=192, HEADS=8, HID=768
#define SSP   49152
#define HDIM  256
#define WDIM  192
#define CDIM  192
#define NHEAD 8
#define CH    24
#define OC3   576
#define HIDF  768
#define NB    4
#define SCCH  24

typedef short bf16x8 __attribute__((ext_vector_type(8)));
typedef short bf16x4 __attribute__((ext_vector_type(4)));
typedef float f32x4  __attribute__((ext_vector_type(4)));

__device__ inline short f2bf(float f) {
  unsigned u = __float_as_uint(f);
  u += 0x7fffu + ((u >> 16) & 1u);
  return (short)(u >> 16);
}
__device__ inline float bf2f(short h) {
  return __uint_as_float(((unsigned)(unsigned short)h) << 16);
}

// ---------------- f32 -> bf16 bulk convert (weights) ----------------
__global__ __launch_bounds__(256) void cvt_bf16(const float* __restrict__ in,
                                                short* __restrict__ out, int n) {
  int i = blockIdx.x * 256 + threadIdx.x;
  if (i < n) out[i] = f2bf(in[i]);
}

// ---------------- LN over channels, single global read (LDS-staged), one batch ----------------
// grid SSP/64, 256 thr. TRANS: out[s][192]; else out[c][s].
template <bool TRANS>
__global__ __launch_bounds__(256) void ln_bf16(const float* __restrict__ xb,
                                               const float* __restrict__ w,
                                               const float* __restrict__ bia,
                                               short* __restrict__ outb) {
  __shared__ float xs[192][68];          // 52,224 B (row 272 B, 16B-aligned)
  __shared__ float ps[4][64], pq[4][64], mus[64], rst[64];
  const int tid = threadIdx.x;
  const int s0 = blockIdx.x * 64;
  // load 192 rows x 16 float4 = 3072 -> 12/thread (coalesced)
#pragma unroll
  for (int it = 0; it < 12; ++it) {
    int u = it * 256 + tid;
    int c = u >> 4, q = u & 15;
    float4 v = *(const float4*)(xb + (size_t)c * SSP + s0 + q * 4);
    *(float4*)&xs[c][q * 4] = v;
  }
  __syncthreads();
  {
    int s = tid & 63, p = tid >> 6;
    float sm = 0.f, sq = 0.f;
    for (int c = p * 48; c < p * 48 + 48; ++c) {
      float v = xs[c][s]; sm += v; sq += v * v;
    }
    ps[p][s] = sm; pq[p][s] = sq;
  }
  __syncthreads();
  if (tid < 64) {
    float sm = ps[0][tid] + ps[1][tid] + ps[2][tid] + ps[3][tid];
    float sq = pq[0][tid] + pq[1][tid] + pq[2][tid] + pq[3][tid];
    float mu = sm * (1.f / CDIM);
    mus[tid] = mu;
    rst[tid] = rsqrtf(sq * (1.f / CDIM) - mu * mu + 1e-5f);
  }
  __syncthreads();
  if (TRANS) {
    // wave-uniform c8, lane = srow -> conflict-free LDS column reads
#pragma unroll
    for (int it = 0; it < 6; ++it) {
      int u = it * 256 + tid;
      int c8 = u >> 6, sr = u & 63;
      float mu = mus[sr], r = rst[sr];
      bf16x8 o;
#pragma unroll
      for (int j = 0; j < 8; ++j) {
        int c = c8 * 8 + j;
        o[j] = f2bf((xs[c][sr] - mu) * r * w[c] + bia[c]);
      }
      *(bf16x8*)(outb + (size_t)(s0 + sr) * CDIM + c8 * 8) = o;
    }
  } else {
#pragma unroll
    for (int it = 0; it < 6; ++it) {
      int u = it * 256 + tid;
      int c = u >> 3, sv = u & 7;
      float wc = w[c], bc = bia[c];
      bf16x8 o;
#pragma unroll
      for (int j = 0; j < 8; ++j) {
        int s = sv * 8 + j;
        o[j] = f2bf((xs[c][s] - mus[s]) * rst[s] * wc + bc);
      }
      *(bf16x8*)(outb + (size_t)c * SSP + s0 + sv * 8) = o;
    }
  }
}

// ---------------- MFMA bf16 GEMM NT (z=1 launches; pointers pre-offset) ----------------
template <int BM, int BN, int WM, int WN, bool RESID, bool OUT_BF16>
__global__ __launch_bounds__(256) void mfma_gemm(
    const short* __restrict__ A, const short* __restrict__ B,
    const float* __restrict__ resid, void* __restrict__ Cv,
    int M, int N, int K) {
  constexpr int BK = 32, PAD = 40;
  constexpr int WTM = BM / WM, WTN = BN / WN;
  constexpr int FM = WTM / 16, FN = WTN / 16;
  static_assert(WM * WN == 4 && BM % 64 == 0 && BN % 64 == 0, "cfg");
  __shared__ short As[BM * PAD];
  __shared__ short Bs[BN * PAD];
  const int tid = threadIdx.x;
  const int m0 = blockIdx.y * BM, n0 = blockIdx.x * BN;
  const int w = tid >> 6, lane = tid & 63;
  const int wm = w / WN, wn = w % WN;
  const int r16 = lane & 15, kg = lane >> 4;
  const int arow = tid >> 2, akc = tid & 3;

  f32x4 acc[FM][FN] = {};

  for (int k0 = 0; k0 < K; k0 += BK) {
#pragma unroll
    for (int i = 0; i < BM; i += 64) {
      bf16x8 v = *(const bf16x8*)(A + (size_t)(m0 + i + arow) * K + k0 + akc * 8);
      *(bf16x8*)(&As[(i + arow) * PAD + akc * 8]) = v;
    }
#pragma unroll
    for (int i = 0; i < BN; i += 64) {
      bf16x8 v = *(const bf16x8*)(B + (size_t)(n0 + i + arow) * K + k0 + akc * 8);
      *(bf16x8*)(&Bs[(i + arow) * PAD + akc * 8]) = v;
    }
    __syncthreads();
    bf16x8 af[FM], bfr[FN];
#pragma unroll
    for (int i = 0; i < FM; ++i)
      af[i] = *(bf16x8*)(&As[(wm * WTM + i * 16 + r16) * PAD + kg * 8]);
#pragma unroll
    for (int j = 0; j < FN; ++j)
      bfr[j] = *(bf16x8*)(&Bs[(wn * WTN + j * 16 + r16) * PAD + kg * 8]);
#pragma unroll
    for (int i = 0; i < FM; ++i)
#pragma unroll
      for (int j = 0; j < FN; ++j)
        acc[i][j] = __builtin_amdgcn_mfma_f32_16x16x32_bf16(af[i], bfr[j], acc[i][j], 0, 0, 0);
    __syncthreads();
  }

  float* Cf = (float*)Cv;
  short* Ch = (short*)Cv;
#pragma unroll
  for (int i = 0; i < FM; ++i) {
#pragma unroll
    for (int j = 0; j < FN; ++j) {
#pragma unroll
      for (int t = 0; t < 4; ++t) {
        int m = m0 + wm * WTM + i * 16 + kg * 4 + t;
        int n = n0 + wn * WTN + j * 16 + r16;
        float v = acc[i][j][t];
        size_t idx = (size_t)m * N + n;
        if (RESID) v += resid[idx];
        if (OUT_BF16) Ch[idx] = f2bf(v); else Cf[idx] = v;
      }
    }
  }
}

// ---------------- 3x3 depthwise conv, LDS-tiled, bf16->bf16 (one batch) ----------------
__global__ __launch_bounds__(256) void dwconv_tile(const short* __restrict__ in,
                                                   const float* __restrict__ w9,
                                                   short* __restrict__ out) {
  __shared__ short tile[34][208];
  const int tid = threadIdx.x;
  const int ch = blockIdx.x >> 3;        // channel 0..575
  const int slab = blockIdx.x & 7;
  const int y0 = slab * 32;
  float wr[9];
#pragma unroll
  for (int i = 0; i < 9; ++i) wr[i] = w9[ch * 9 + i];
  const short* ip = in + (size_t)ch * SSP;

  if (tid < 34) { tile[tid][7] = 0; tile[tid][200] = 0; }
#pragma unroll
  for (int i = 0; i < 4; ++i) {
    int idx = i * 256 + tid;
    if (idx < 816) {
      int row = idx / 24, cx = idx - row * 24;
      int gy = y0 + row - 1;
      bf16x8 v = {};
      if (gy >= 0 && gy < HDIM) v = *(const bf16x8*)(ip + gy * WDIM + cx * 8);
      *(bf16x8*)(&tile[row][8 + cx * 8]) = v;
    }
  }
  __syncthreads();

  short* op = out + (size_t)ch * SSP;
#pragma unroll
  for (int g = 0; g < 3; ++g) {
    int G = g * 256 + tid;
    int r = G / 24, cx = G - (G / 24) * 24;
    int cb = cx * 8 + 7;
    float a[10], b[10], c[10];
#pragma unroll
    for (int d = 0; d < 10; ++d) {
      a[d] = bf2f(tile[r][cb + d]);
      b[d] = bf2f(tile[r + 1][cb + d]);
      c[d] = bf2f(tile[r + 2][cb + d]);
    }
    bf16x8 ov;
#pragma unroll
    for (int j = 0; j < 8; ++j) {
      float acc = wr[0] * a[j] + wr[1] * a[j + 1] + wr[2] * a[j + 2]
                + wr[3] * b[j] + wr[4] * b[j + 1] + wr[5] * b[j + 2]
                + wr[6] * c[j] + wr[7] * c[j + 1] + wr[8] * c[j + 2];
      ov[j] = f2bf(acc);
    }
    *(bf16x8*)(op + (y0 + r) * WDIM + cx * 8) = ov;
  }
}

// ---------------- scores stage1 (one batch; pointers pre-offset) ----------------
__global__ __launch_bounds__(256) void scores_stage1(const short* __restrict__ D,
                                                     float* __restrict__ pdot,
                                                     float* __restrict__ qss,
                                                     float* __restrict__ kss) {
  int ch = blockIdx.x, h = blockIdx.y;
  __shared__ float qs[24][260];
  __shared__ float ks[24][260];
  int tid = threadIdx.x;
  int w = tid >> 6, lane = tid & 63;
  int c0 = w * 6;
  float acc[6] = {0.f, 0.f, 0.f, 0.f, 0.f, 0.f};
  float ssacc = 0.f;
  const short* qb = D + (size_t)(h * CH) * SSP;
  const short* kb = D + (size_t)(CDIM + h * CH) * SSP;
  for (int it = 0; it < 8; ++it) {
    int s0 = ch * 2048 + it * 256;
#pragma unroll
    for (int p = 0; p < 3; ++p) {
      int u = p * 256 + tid;
      int row = u >> 5, col8 = u & 31;
      bf16x8 qv = *(const bf16x8*)(qb + (size_t)row * SSP + s0 + col8 * 8);
      bf16x8 kv = *(const bf16x8*)(kb + (size_t)row * SSP + s0 + col8 * 8);
#pragma unroll
      for (int j = 0; j < 8; ++j) {
        qs[row][col8 * 8 + j] = bf2f(qv[j]);
        ks[row][col8 * 8 + j] = bf2f(kv[j]);
      }
    }
    __syncthreads();
    if (w < 2 && lane < 24) {
      const float (*src)[260] = (w == 0) ? qs : ks;
      for (int s = 0; s < 256; s += 4) {
        float4 v = *(const float4*)&src[lane][s];
        ssacc += v.x * v.x + v.y * v.y + v.z * v.z + v.w * v.w;
      }
    }
    if (lane < 24) {
      for (int s = 0; s < 256; s += 4) {
        float4 kv = *(float4*)&ks[lane][s];
#pragma unroll
        for (int i = 0; i < 6; ++i) {
          float4 qv = *(float4*)&qs[c0 + i][s];
          acc[i] += qv.x * kv.x + qv.y * kv.y + qv.z * kv.z + qv.w * kv.w;
        }
      }
    }
    __syncthreads();
  }
  if (lane < 24) {
#pragma unroll
    for (int i = 0; i < 6; ++i)
      pdot[(((size_t)h * CH + (c0 + i)) * CH + lane) * SCCH + ch] = acc[i];
    if (w == 0) qss[((size_t)h * CH + lane) * SCCH + ch] = ssacc;
    if (w == 1) kss[((size_t)h * CH + lane) * SCCH + ch] = ssacc;
  }
}

// ---------------- scores reduce + norms + temperature + softmax (one batch) ----------------
__global__ void scores_reduce(const float* __restrict__ pdot,
                              const float* __restrict__ qss,
                              const float* __restrict__ kss,
                              const float* __restrict__ temp,
                              float* __restrict__ atn) {
  int c = blockIdx.x, h = blockIdx.y;
  int tid = threadIdx.x;   // 64
  __shared__ float row[24];
  if (tid < 24) {
    const float* p = pdot + (((size_t)h * CH + c) * CH + tid) * SCCH;
    float s = 0.f;
#pragma unroll
    for (int i = 0; i < SCCH; ++i) s += p[i];
    const float* pq = qss + ((size_t)h * CH + c) * SCCH;
    const float* pk = kss + ((size_t)h * CH + tid) * SCCH;
    float sq = 0.f, sk = 0.f;
#pragma unroll
    for (int i = 0; i < SCCH; ++i) { sq += pq[i]; sk += pk[i]; }
    float rq = 1.f / fmaxf(sqrtf(sq), 1e-12f);
    float rk = 1.f / fmaxf(sqrtf(sk), 1e-12f);
    row[tid] = s * rq * rk * temp[h];
  }
  __syncthreads();
  if (tid < 24) {
    float mx = -1e30f;
    for (int d = 0; d < 24; ++d) mx = fmaxf(mx, row[d]);
    float sum = 0.f;
    for (int d = 0; d < 24; ++d) sum += expf(row[d] - mx);
    atn[(size_t)h * 576 + c * CH + tid] = expf(row[tid] - mx) / sum;
  }
}

// ---------------- PV -> pvt bf16 [s][192] (one batch) ----------------
__global__ __launch_bounds__(256) void attn_pv_bf16(const short* __restrict__ D,
                                                    const float* __restrict__ atn,
                                                    short* __restrict__ pvt) {
  int nb = blockIdx.x, h = blockIdx.y;
  __shared__ float aL[24][24];
  int tid = threadIdx.x;
  const float* ab = atn + (size_t)h * 576;
  for (int i = tid; i < 576; i += 256) aL[i / 24][i % 24] = ab[i];
  __syncthreads();
  int n = nb * 256 + tid;
  const short* vb = D + (size_t)(2 * CDIM + h * CH) * SSP + n;
  float vv[24];
#pragma unroll
  for (int d = 0; d < 24; ++d) vv[d] = bf2f(vb[(size_t)d * SSP]);
  short* ob = pvt + (size_t)n * CDIM + h * CH;
  bf16x8 o0, o1, o2;
#pragma unroll
  for (int cc = 0; cc < 24; ++cc) {
    float s = 0.f;
#pragma unroll
    for (int d = 0; d < 24; ++d) s += aL[cc][d] * vv[d];
    short bv = f2bf(s);
    if (cc < 8) o0[cc & 7] = bv; else if (cc < 16) o1[cc & 7] = bv; else o2[cc & 7] = bv;
  }
  *(bf16x8*)(ob) = o0;
  *(bf16x8*)(ob + 8) = o1;
  *(bf16x8*)(ob + 16) = o2;
}

// ---------------- fused MLP v4: reg-hoisted y2 frags + double-buffered weights ----------------
// out[m][0..191] += gelu(y2[m][:] @ w1^T + b1) @ w2^T + b2 ; 128 rows/block, 512 thr.
// smem layout (shorts): buf0 [0,26624) = w1[64*200] + w2[192*72]; buf1 [26624,53248);
// h1s [53248, 62464). y2 tile staged into buf1 region, dead after frag hoist.
__global__ __launch_bounds__(512) void mlp_fused(const short* __restrict__ y2,
                                                 const short* __restrict__ w1,
                                                 const short* __restrict__ w2,
                                                 const float* __restrict__ b1,
                                                 const float* __restrict__ b2,
                                                 float* __restrict__ out) {
  __shared__ short smem[62464];          // 124,928 B
  short* h1s = smem + 53248;
  const int tid = threadIdx.x;
  const int m0 = blockIdx.x * 128;
  const int w = tid >> 6, lane = tid & 63;
  const int r16 = lane & 15, kg = lane >> 4;
  const int wm = w >> 1, wn = w & 1;

  const int u0 = tid, u1 = 512 + tid, u2 = 1024 + tid;
  const int s1r[3] = {u0 / 24, u1 / 24, u2 / 24};
  const int s1c[3] = {u0 % 24, u1 % 24, u2 % 24};
  const int s2r[3] = {u0 / 8, u1 / 8, u2 / 8};
  const int s2c[3] = {u0 % 8, u1 % 8, u2 % 8};

  // stage y2 tile into buf1 region (temporarily)
  short* y2s = smem + 26624;
#pragma unroll
  for (int it = 0; it < 6; ++it) {
    int u = it * 512 + tid;
    int row = u / 24, cx = u % 24;
    *(bf16x8*)(&y2s[row * 200 + cx * 8]) =
        *(const bf16x8*)(y2 + (size_t)(m0 + row) * CDIM + cx * 8);
  }
  // stage chunk-0 weights into buf0
#pragma unroll
  for (int it = 0; it < 3; ++it) {
    *(bf16x8*)(&smem[s1r[it] * 200 + s1c[it] * 8]) =
        *(const bf16x8*)(w1 + (size_t)s1r[it] * CDIM + s1c[it] * 8);
    *(bf16x8*)(&smem[12800 + s2r[it] * 72 + s2c[it] * 8]) =
        *(const bf16x8*)(w2 + (size_t)s2r[it] * HIDF + s2c[it] * 8);
  }
  __syncthreads();

  // hoist y2 fragments (reused by all 12 chunks); y2s region dead after
  bf16x8 afr[2][6];
#pragma unroll
  for (int ks = 0; ks < 6; ++ks)
#pragma unroll
    for (int i = 0; i < 2; ++i)
      afr[i][ks] = *(bf16x8*)(&y2s[(wm * 32 + i * 16 + r16) * 200 + ks * 32 + kg * 8]);

  f32x4 bacc[2][6] = {};
  bf16x8 rw1[3], rw2[3];

  for (int hc = 0; hc < 12; ++hc) {
    short* bw1 = smem + (hc & 1) * 26624;
    short* bw2 = bw1 + 12800;
    short* nw1 = smem + ((hc & 1) ^ 1) * 26624;
    short* nw2 = nw1 + 12800;
    if (hc < 11) {     // issue next chunk's weight loads (hide under phases A+B)
#pragma unroll
      for (int it = 0; it < 3; ++it) {
        rw1[it] = *(const bf16x8*)(w1 + (size_t)((hc + 1) * 64 + s1r[it]) * CDIM + s1c[it] * 8);
        rw2[it] = *(const bf16x8*)(w2 + (size_t)s2r[it] * HIDF + (hc + 1) * 64 + s2c[it] * 8);
      }
    }
    // phase A (swapped): D[hid][m]; only bg read from LDS
    f32x4 pacc[2][2] = {};
#pragma unroll
    for (int ks = 0; ks < 6; ++ks) {
      bf16x8 bg[2];
#pragma unroll
      for (int j = 0; j < 2; ++j)
        bg[j] = *(bf16x8*)(&bw1[(wn * 32 + j * 16 + r16) * 200 + ks * 32 + kg * 8]);
#pragma unroll
      for (int i = 0; i < 2; ++i)
#pragma unroll
        for (int j = 0; j < 2; ++j)
          pacc[i][j] = __builtin_amdgcn_mfma_f32_16x16x32_bf16(bg[j], afr[i][ks], pacc[i][j], 0, 0, 0);
    }
    // bias + gelu (tanh form) -> h1s packed b64 writes
#pragma unroll
    for (int i = 0; i < 2; ++i) {
      int mr = wm * 32 + i * 16 + r16;
#pragma unroll
      for (int j = 0; j < 2; ++j) {
        int hid0 = wn * 32 + j * 16 + kg * 4;
        bf16x4 pk;
#pragma unroll
        for (int t = 0; t < 4; ++t) {
          float v = pacc[i][j][t] + b1[hc * 64 + hid0 + t];
          float u = v * (0.7978845608f + 0.0356774081f * v * v);
          v = v / (1.f + __expf(-2.f * u));
          pk[t] = f2bf(v);
        }
        *(bf16x4*)(&h1s[mr * 72 + hid0]) = pk;
      }
    }
    __syncthreads();   // h1s ready
    // phase B: bacc += h1s @ w2s^T
#pragma unroll
    for (int ks = 0; ks < 2; ++ks) {
      bf16x8 a2[2];
#pragma unroll
      for (int i = 0; i < 2; ++i)
        a2[i] = *(bf16x8*)(&h1s[(wm * 32 + i * 16 + r16) * 72 + ks * 32 + kg * 8]);
#pragma unroll
      for (int j = 0; j < 6; ++j) {
        bf16x8 b2g = *(bf16x8*)(&bw2[(wn * 96 + j * 16 + r16) * 72 + ks * 32 + kg * 8]);
#pragma unroll
        for (int i = 0; i < 2; ++i)
          bacc[i][j] = __builtin_amdgcn_mfma_f32_16x16x32_bf16(a2[i], b2g, bacc[i][j], 0, 0, 0);
      }
    }
    // write prefetched regs into the OTHER buffer (no read hazard)
    if (hc < 11) {
#pragma unroll
      for (int it = 0; it < 3; ++it) {
        *(bf16x8*)(&nw1[s1r[it] * 200 + s1c[it] * 8]) = rw1[it];
        *(bf16x8*)(&nw2[s2r[it] * 72 + s2c[it] * 8]) = rw2[it];
      }
    }
    __syncthreads();   // next buf ready; h1s reads done
  }

  // epilogue: out += bacc + b2 (out holds x1 residual)
#pragma unroll
  for (int i = 0; i < 2; ++i)
#pragma unroll
    for (int j = 0; j < 6; ++j)
#pragma unroll
      for (int t = 0; t < 4; ++t) {
        int m = m0 + wm * 32 + i * 16 + kg * 4 + t;
        int n = wn * 96 + j * 16 + r16;
        size_t idx = (size_t)m * CDIM + n;
        out[idx] = bacc[i][j][t] + b2[n] + out[idx];
      }
}

extern "C" void kernel_launch(void* const* d_in, const int* in_sizes, int n_in,
                              void* d_out, int out_size, void* d_ws, size_t ws_size,
                              hipStream_t stream) {
  const float* x      = (const float*)d_in[0];
  const float* ln1_w  = (const float*)d_in[1];
  const float* ln1_b  = (const float*)d_in[2];
  const float* temp   = (const float*)d_in[3];
  const float* qkv_w  = (const float*)d_in[4];
  const float* dw_w   = (const float*)d_in[5];
  const float* proj_w = (const float*)d_in[6];
  const float* ln2_w  = (const float*)d_in[7];
  const float* ln2_b  = (const float*)d_in[8];
  const float* fc1_w  = (const float*)d_in[9];
  const float* fc1_b  = (const float*)d_in[10];
  const float* fc2_w  = (const float*)d_in[11];
  const float* fc2_b  = (const float*)d_in[12];
  float* out = (float*)d_out;

  const size_t BSZ  = (size_t)CDIM * SSP;   // 9,437,184
  const size_t B3SZ = (size_t)OC3 * SSP;    // 28,311,552
  char* base = (char*)d_ws;
  short* wq  = (short*)base;
  short* wp  = wq + 110592;
  short* w1  = wp + 36864;
  short* w2  = w1 + 147456;
  float* pdot= (float*)(base + 890880);
  float* qss = (float*)(base + 2660352);
  float* kss = (float*)(base + 2734080);
  float* atn = (float*)(base + 2807808);
  short* Dv  = (short*)(base + 4194304);         // [4][576][SSP] bf16
  short* y1t = Dv;                               // per-batch [SSP][192] overlay
  short* T   = (short*)(base + 230686720);       // [4][576][SSP] bf16
  short* pvt = T;                                // per-batch overlay
  short* y2  = (short*)(base + 457179136);       // [4][192][SSP] bf16

  // weights -> bf16
  cvt_bf16<<<dim3(432), 256, 0, stream>>>(qkv_w, wq, 110592);
  cvt_bf16<<<dim3(144), 256, 0, stream>>>(proj_w, wp, 36864);
  cvt_bf16<<<dim3(576), 256, 0, stream>>>(fc1_w, w1, 147456);
  cvt_bf16<<<dim3(576), 256, 0, stream>>>(fc2_w, w2, 147456);

  // per-batch chain: working sets (75-226 MB) stay L3-resident between stages
  for (int b = 0; b < NB; ++b) {
    const float* xb  = x + (size_t)b * BSZ;
    float* outb      = out + (size_t)b * BSZ;
    short* y1tb      = y1t + (size_t)b * BSZ;
    short* Tb        = T + (size_t)b * B3SZ;
    short* Dvb       = Dv + (size_t)b * B3SZ;
    short* pvtb      = pvt + (size_t)b * BSZ;
    short* y2b       = y2 + (size_t)b * BSZ;
    float* pdotb     = pdot + (size_t)b * (NHEAD * CH * CH * SCCH);
    float* qssb      = qss + (size_t)b * (NHEAD * CH * SCCH);
    float* kssb      = kss + (size_t)b * (NHEAD * CH * SCCH);
    float* atnb      = atn + (size_t)b * (NHEAD * 576);

    ln_bf16<true><<<dim3(SSP / 64), 256, 0, stream>>>(xb, ln1_w, ln1_b, y1tb);
    mfma_gemm<64, 256, 1, 4, false, true><<<dim3(SSP / 256, OC3 / 64), 256, 0, stream>>>(
        wq, y1tb, nullptr, Tb, OC3, SSP, CDIM);
    dwconv_tile<<<dim3(OC3 * 8), 256, 0, stream>>>(Tb, dw_w, Dvb);
    scores_stage1<<<dim3(SCCH, NHEAD), 256, 0, stream>>>(Dvb, pdotb, qssb, kssb);
    scores_reduce<<<dim3(CH, NHEAD), 64, 0, stream>>>(pdotb, qssb, kssb, temp, atnb);
    attn_pv_bf16<<<dim3(SSP / 256, NHEAD), 256, 0, stream>>>(Dvb, atnb, pvtb);
    mfma_gemm<64, 256, 1, 4, true, false><<<dim3(SSP / 256, CDIM / 64), 256, 0, stream>>>(
        wp, pvtb, xb, outb, CDIM, SSP, CDIM);
    ln_bf16<false><<<dim3(SSP / 64), 256, 0, stream>>>(outb, ln2_w, ln2_b, y2b);
  }
  // fused MLP (batched; y2 read once into regs/LDS)
  mlp_fused<<<dim3(196608 / 128), 512, 0, stream>>>(y2, w1, w2, fc1_b, fc2_b, out);
}

// Round 10
// 1079.371 us; speedup vs baseline: 1.1140x; 1.1140x over previous
//
#include <hip/hip_runtime.h>
#include <math.h>

// TransformerBlock1: b=4, DIM=192, h=256, w=192, HEADS=8, HID=768
#define SSP   49152
#define HDIM  256
#define WDIM  192
#define CDIM  192
#define NHEAD 8
#define CH    24
#define OC3   576
#define HIDF  768
#define NB    4
#define SCCH  24

typedef short bf16x8 __attribute__((ext_vector_type(8)));
typedef short bf16x4 __attribute__((ext_vector_type(4)));
typedef float f32x4  __attribute__((ext_vector_type(4)));

__device__ inline short f2bf(float f) {
  unsigned u = __float_as_uint(f);
  u += 0x7fffu + ((u >> 16) & 1u);
  return (short)(u >> 16);
}
__device__ inline float bf2f(short h) {
  return __uint_as_float(((unsigned)(unsigned short)h) << 16);
}

// ---------------- f32 -> bf16 bulk convert (weights) ----------------
__global__ __launch_bounds__(256) void cvt_bf16(const float* __restrict__ in,
                                                short* __restrict__ out, int n) {
  int i = blockIdx.x * 256 + threadIdx.x;
  if (i < n) out[i] = f2bf(in[i]);
}

// ---------------- LN over channels, single global read, batched over y ----------------
// grid (SSP/64, NB), 256 thr. TRANS: out[s][192]; else out[c][s].
template <bool TRANS>
__global__ __launch_bounds__(256) void ln_bf16(const float* __restrict__ x,
                                               const float* __restrict__ w,
                                               const float* __restrict__ bia,
                                               short* __restrict__ outp) {
  __shared__ float xs[192][68];
  __shared__ float ps[4][64], pq[4][64], mus[64], rst[64];
  const int tid = threadIdx.x;
  const int s0 = blockIdx.x * 64;
  const float* xb = x + (size_t)blockIdx.y * CDIM * SSP;
  short* outb = outp + (size_t)blockIdx.y * CDIM * SSP;
#pragma unroll
  for (int it = 0; it < 12; ++it) {
    int u = it * 256 + tid;
    int c = u >> 4, q = u & 15;
    float4 v = *(const float4*)(xb + (size_t)c * SSP + s0 + q * 4);
    *(float4*)&xs[c][q * 4] = v;
  }
  __syncthreads();
  {
    int s = tid & 63, p = tid >> 6;
    float sm = 0.f, sq = 0.f;
    for (int c = p * 48; c < p * 48 + 48; ++c) {
      float v = xs[c][s]; sm += v; sq += v * v;
    }
    ps[p][s] = sm; pq[p][s] = sq;
  }
  __syncthreads();
  if (tid < 64) {
    float sm = ps[0][tid] + ps[1][tid] + ps[2][tid] + ps[3][tid];
    float sq = pq[0][tid] + pq[1][tid] + pq[2][tid] + pq[3][tid];
    float mu = sm * (1.f / CDIM);
    mus[tid] = mu;
    rst[tid] = rsqrtf(sq * (1.f / CDIM) - mu * mu + 1e-5f);
  }
  __syncthreads();
  if (TRANS) {
#pragma unroll
    for (int it = 0; it < 6; ++it) {
      int u = it * 256 + tid;
      int c8 = u >> 6, sr = u & 63;
      float mu = mus[sr], r = rst[sr];
      bf16x8 o;
#pragma unroll
      for (int j = 0; j < 8; ++j) {
        int c = c8 * 8 + j;
        o[j] = f2bf((xs[c][sr] - mu) * r * w[c] + bia[c]);
      }
      *(bf16x8*)(outb + (size_t)(s0 + sr) * CDIM + c8 * 8) = o;
    }
  } else {
#pragma unroll
    for (int it = 0; it < 6; ++it) {
      int u = it * 256 + tid;
      int c = u >> 3, sv = u & 7;
      float wc = w[c], bc = bia[c];
      bf16x8 o;
#pragma unroll
      for (int j = 0; j < 8; ++j) {
        int s = sv * 8 + j;
        o[j] = f2bf((xs[c][s] - mus[s]) * rst[s] * wc + bc);
      }
      *(bf16x8*)(outb + (size_t)c * SSP + s0 + sv * 8) = o;
    }
  }
}

// ---------------- MFMA bf16 GEMM NT, batched over z ----------------
template <int BM, int BN, int WM, int WN, bool RESID, bool OUT_BF16>
__global__ __launch_bounds__(256) void mfma_gemm(
    const short* __restrict__ A, const short* __restrict__ B,
    const float* __restrict__ resid, void* __restrict__ Cv,
    int M, int N, int K, long long strideB, long long strideC) {
  constexpr int BK = 32, PAD = 40;
  constexpr int WTM = BM / WM, WTN = BN / WN;
  constexpr int FM = WTM / 16, FN = WTN / 16;
  static_assert(WM * WN == 4 && BM % 64 == 0 && BN % 64 == 0, "cfg");
  __shared__ short As[BM * PAD];
  __shared__ short Bs[BN * PAD];
  const int tid = threadIdx.x;
  const int m0 = blockIdx.y * BM, n0 = blockIdx.x * BN;
  const long long z = blockIdx.z;
  const short* Bz = B + z * strideB;
  const int w = tid >> 6, lane = tid & 63;
  const int wm = w / WN, wn = w % WN;
  const int r16 = lane & 15, kg = lane >> 4;
  const int arow = tid >> 2, akc = tid & 3;

  f32x4 acc[FM][FN] = {};

  for (int k0 = 0; k0 < K; k0 += BK) {
#pragma unroll
    for (int i = 0; i < BM; i += 64) {
      bf16x8 v = *(const bf16x8*)(A + (size_t)(m0 + i + arow) * K + k0 + akc * 8);
      *(bf16x8*)(&As[(i + arow) * PAD + akc * 8]) = v;
    }
#pragma unroll
    for (int i = 0; i < BN; i += 64) {
      bf16x8 v = *(const bf16x8*)(Bz + (size_t)(n0 + i + arow) * K + k0 + akc * 8);
      *(bf16x8*)(&Bs[(i + arow) * PAD + akc * 8]) = v;
    }
    __syncthreads();
    bf16x8 af[FM], bfr[FN];
#pragma unroll
    for (int i = 0; i < FM; ++i)
      af[i] = *(bf16x8*)(&As[(wm * WTM + i * 16 + r16) * PAD + kg * 8]);
#pragma unroll
    for (int j = 0; j < FN; ++j)
      bfr[j] = *(bf16x8*)(&Bs[(wn * WTN + j * 16 + r16) * PAD + kg * 8]);
#pragma unroll
    for (int i = 0; i < FM; ++i)
#pragma unroll
      for (int j = 0; j < FN; ++j)
        acc[i][j] = __builtin_amdgcn_mfma_f32_16x16x32_bf16(af[i], bfr[j], acc[i][j], 0, 0, 0);
    __syncthreads();
  }

  float* Cf = (float*)Cv + z * strideC;
  short* Ch = (short*)Cv + z * strideC;
  const float* R = RESID ? resid + z * strideC : nullptr;
#pragma unroll
  for (int i = 0; i < FM; ++i) {
#pragma unroll
    for (int j = 0; j < FN; ++j) {
#pragma unroll
      for (int t = 0; t < 4; ++t) {
        int m = m0 + wm * WTM + i * 16 + kg * 4 + t;
        int n = n0 + wn * WTN + j * 16 + r16;
        float v = acc[i][j][t];
        size_t idx = (size_t)m * N + n;
        if (RESID) v += R[idx];
        if (OUT_BF16) Ch[idx] = f2bf(v); else Cf[idx] = v;
      }
    }
  }
}

// ---------------- 3x3 depthwise conv, LDS-tiled, bf16->bf16, batched ----------------
__global__ __launch_bounds__(256) void dwconv_tile(const short* __restrict__ in,
                                                   const float* __restrict__ w9,
                                                   short* __restrict__ out) {
  __shared__ short tile[34][208];
  const int tid = threadIdx.x;
  const int ch = blockIdx.x >> 3;        // b*OC3 + o
  const int slab = blockIdx.x & 7;
  const int o = ch % OC3;
  const int y0 = slab * 32;
  float wr[9];
#pragma unroll
  for (int i = 0; i < 9; ++i) wr[i] = w9[o * 9 + i];
  const short* ip = in + (size_t)ch * SSP;

  if (tid < 34) { tile[tid][7] = 0; tile[tid][200] = 0; }
#pragma unroll
  for (int i = 0; i < 4; ++i) {
    int idx = i * 256 + tid;
    if (idx < 816) {
      int row = idx / 24, cx = idx - row * 24;
      int gy = y0 + row - 1;
      bf16x8 v = {};
      if (gy >= 0 && gy < HDIM) v = *(const bf16x8*)(ip + gy * WDIM + cx * 8);
      *(bf16x8*)(&tile[row][8 + cx * 8]) = v;
    }
  }
  __syncthreads();

  short* op = out + (size_t)ch * SSP;
#pragma unroll
  for (int g = 0; g < 3; ++g) {
    int G = g * 256 + tid;
    int r = G / 24, cx = G - (G / 24) * 24;
    int cb = cx * 8 + 7;
    float a[10], b[10], c[10];
#pragma unroll
    for (int d = 0; d < 10; ++d) {
      a[d] = bf2f(tile[r][cb + d]);
      b[d] = bf2f(tile[r + 1][cb + d]);
      c[d] = bf2f(tile[r + 2][cb + d]);
    }
    bf16x8 ov;
#pragma unroll
    for (int j = 0; j < 8; ++j) {
      float acc = wr[0] * a[j] + wr[1] * a[j + 1] + wr[2] * a[j + 2]
                + wr[3] * b[j] + wr[4] * b[j + 1] + wr[5] * b[j + 2]
                + wr[6] * c[j] + wr[7] * c[j + 1] + wr[8] * c[j + 2];
      ov[j] = f2bf(acc);
    }
    *(bf16x8*)(op + (y0 + r) * WDIM + cx * 8) = ov;
  }
}

// ---------------- scores stage1: partial dots + per-row sumsq chunks (batched z) ----------------
__global__ __launch_bounds__(256) void scores_stage1(const short* __restrict__ D,
                                                     float* __restrict__ pdot,
                                                     float* __restrict__ qss,
                                                     float* __restrict__ kss) {
  int ch = blockIdx.x, h = blockIdx.y, b = blockIdx.z;
  __shared__ float qs[24][260];
  __shared__ float ks[24][260];
  int tid = threadIdx.x;
  int w = tid >> 6, lane = tid & 63;
  int c0 = w * 6;
  float acc[6] = {0.f, 0.f, 0.f, 0.f, 0.f, 0.f};
  float ssacc = 0.f;
  const short* qb = D + ((size_t)b * OC3 + h * CH) * SSP;
  const short* kb = D + ((size_t)b * OC3 + CDIM + h * CH) * SSP;
  for (int it = 0; it < 8; ++it) {
    int s0 = ch * 2048 + it * 256;
#pragma unroll
    for (int p = 0; p < 3; ++p) {
      int u = p * 256 + tid;
      int row = u >> 5, col8 = u & 31;
      bf16x8 qv = *(const bf16x8*)(qb + (size_t)row * SSP + s0 + col8 * 8);
      bf16x8 kv = *(const bf16x8*)(kb + (size_t)row * SSP + s0 + col8 * 8);
#pragma unroll
      for (int j = 0; j < 8; ++j) {
        qs[row][col8 * 8 + j] = bf2f(qv[j]);
        ks[row][col8 * 8 + j] = bf2f(kv[j]);
      }
    }
    __syncthreads();
    if (w < 2 && lane < 24) {
      const float (*src)[260] = (w == 0) ? qs : ks;
      for (int s = 0; s < 256; s += 4) {
        float4 v = *(const float4*)&src[lane][s];
        ssacc += v.x * v.x + v.y * v.y + v.z * v.z + v.w * v.w;
      }
    }
    if (lane < 24) {
      for (int s = 0; s < 256; s += 4) {
        float4 kv = *(float4*)&ks[lane][s];
#pragma unroll
        for (int i = 0; i < 6; ++i) {
          float4 qv = *(float4*)&qs[c0 + i][s];
          acc[i] += qv.x * kv.x + qv.y * kv.y + qv.z * kv.z + qv.w * kv.w;
        }
      }
    }
    __syncthreads();
  }
  if (lane < 24) {
    float* pb = pdot + (size_t)b * (NHEAD * CH * CH * SCCH);
#pragma unroll
    for (int i = 0; i < 6; ++i)
      pb[(((size_t)h * CH + (c0 + i)) * CH + lane) * SCCH + ch] = acc[i];
    if (w == 0) qss[(((size_t)b * NHEAD + h) * CH + lane) * SCCH + ch] = ssacc;
    if (w == 1) kss[(((size_t)b * NHEAD + h) * CH + lane) * SCCH + ch] = ssacc;
  }
}

// ---------------- scores reduce + norms + temperature + softmax (batched z) ----------------
__global__ void scores_reduce(const float* __restrict__ pdot,
                              const float* __restrict__ qss,
                              const float* __restrict__ kss,
                              const float* __restrict__ temp,
                              float* __restrict__ atn) {
  int c = blockIdx.x, h = blockIdx.y, b = blockIdx.z;
  int tid = threadIdx.x;   // 64
  __shared__ float row[24];
  if (tid < 24) {
    const float* p = pdot + (size_t)b * (NHEAD * CH * CH * SCCH) +
                     (((size_t)h * CH + c) * CH + tid) * SCCH;
    float s = 0.f;
#pragma unroll
    for (int i = 0; i < SCCH; ++i) s += p[i];
    const float* pq = qss + (((size_t)b * NHEAD + h) * CH + c) * SCCH;
    const float* pk = kss + (((size_t)b * NHEAD + h) * CH + tid) * SCCH;
    float sq = 0.f, sk = 0.f;
#pragma unroll
    for (int i = 0; i < SCCH; ++i) { sq += pq[i]; sk += pk[i]; }
    float rq = 1.f / fmaxf(sqrtf(sq), 1e-12f);
    float rk = 1.f / fmaxf(sqrtf(sk), 1e-12f);
    row[tid] = s * rq * rk * temp[h];
  }
  __syncthreads();
  if (tid < 24) {
    float mx = -1e30f;
    for (int d = 0; d < 24; ++d) mx = fmaxf(mx, row[d]);
    float sum = 0.f;
    for (int d = 0; d < 24; ++d) sum += expf(row[d] - mx);
    atn[((size_t)b * NHEAD + h) * 576 + c * CH + tid] = expf(row[tid] - mx) / sum;
  }
}

// ---------------- PV -> pvt bf16 [b][s][192] (batched z) ----------------
__global__ __launch_bounds__(256) void attn_pv_bf16(const short* __restrict__ D,
                                                    const float* __restrict__ atn,
                                                    short* __restrict__ pvt) {
  int nb = blockIdx.x, h = blockIdx.y, b = blockIdx.z;
  __shared__ float aL[24][24];
  int tid = threadIdx.x;
  const float* ab = atn + ((size_t)b * NHEAD + h) * 576;
  for (int i = tid; i < 576; i += 256) aL[i / 24][i % 24] = ab[i];
  __syncthreads();
  int n = nb * 256 + tid;
  const short* vb = D + ((size_t)b * OC3 + 2 * CDIM + h * CH) * SSP + n;
  float vv[24];
#pragma unroll
  for (int d = 0; d < 24; ++d) vv[d] = bf2f(vb[(size_t)d * SSP]);
  short* ob = pvt + (size_t)b * SSP * CDIM + (size_t)n * CDIM + h * CH;
  bf16x8 o0, o1, o2;
#pragma unroll
  for (int cc = 0; cc < 24; ++cc) {
    float s = 0.f;
#pragma unroll
    for (int d = 0; d < 24; ++d) s += aL[cc][d] * vv[d];
    short bv = f2bf(s);
    if (cc < 8) o0[cc & 7] = bv; else if (cc < 16) o1[cc & 7] = bv; else o2[cc & 7] = bv;
  }
  *(bf16x8*)(ob) = o0;
  *(bf16x8*)(ob + 8) = o1;
  *(bf16x8*)(ob + 16) = o2;
}

// ---------------- fused MLP v5: 64-row blocks, 256 thr, <64KB LDS -> 2 blocks/CU ----------------
// out[m][0..191] += gelu(y2[m][:] @ w1^T + b1) @ w2^T + b2
// Single weight buffer + reg prefetch; write-backs scheduled so only 2 barriers/chunk:
//   [issue rw][phaseA->h1s][bar1][rw1->w1s ; phaseB][bar2][rw2->w2s]
// (rw2 visibility for next phaseB is covered by next chunk's bar1.)
__global__ __launch_bounds__(256) void mlp_fused(const short* __restrict__ y2,
                                                 const short* __restrict__ w1,
                                                 const short* __restrict__ w2,
                                                 const float* __restrict__ b1,
                                                 const float* __restrict__ b2,
                                                 float* __restrict__ out) {
  __shared__ short w1s[64 * 200];   // 25600 B
  __shared__ short w2s[192 * 72];   // 27648 B
  __shared__ short h1s[64 * 72];    //  9216 B   -> 62464 B total (2 blocks/CU)
  const int tid = threadIdx.x;
  const int m0 = blockIdx.x * 64;
  const int w = tid >> 6, lane = tid & 63;
  const int r16 = lane & 15, kg = lane >> 4;
  const int wm = w >> 1, wn = w & 1;

  int s1r[6], s1c[6], s2r[6], s2c[6];
#pragma unroll
  for (int it = 0; it < 6; ++it) {
    int u = it * 256 + tid;          // < 1536
    s1r[it] = u / 24; s1c[it] = u % 24;
    s2r[it] = u / 8;  s2c[it] = u % 8;
  }

  // y2 fragments direct from global (read-once data), reused all 12 chunks
  bf16x8 afr[2][6];
#pragma unroll
  for (int ks = 0; ks < 6; ++ks)
#pragma unroll
    for (int i = 0; i < 2; ++i)
      afr[i][ks] = *(const bf16x8*)(y2 + (size_t)(m0 + wm * 32 + i * 16 + r16) * CDIM + ks * 32 + kg * 8);

  // stage chunk-0 weights
#pragma unroll
  for (int it = 0; it < 6; ++it) {
    *(bf16x8*)(&w1s[s1r[it] * 200 + s1c[it] * 8]) =
        *(const bf16x8*)(w1 + (size_t)s1r[it] * CDIM + s1c[it] * 8);
    *(bf16x8*)(&w2s[s2r[it] * 72 + s2c[it] * 8]) =
        *(const bf16x8*)(w2 + (size_t)s2r[it] * HIDF + s2c[it] * 8);
  }
  __syncthreads();

  f32x4 bacc[2][6] = {};
  bf16x8 rw1[6], rw2[6];

  for (int hc = 0; hc < 12; ++hc) {
    if (hc < 11) {   // issue next chunk's weight loads early
#pragma unroll
      for (int it = 0; it < 6; ++it) {
        rw1[it] = *(const bf16x8*)(w1 + (size_t)((hc + 1) * 64 + s1r[it]) * CDIM + s1c[it] * 8);
        rw2[it] = *(const bf16x8*)(w2 + (size_t)s2r[it] * HIDF + (hc + 1) * 64 + s2c[it] * 8);
      }
    }
    // phase A (swapped): D[hid][m]
    f32x4 pacc[2][2] = {};
#pragma unroll
    for (int ks = 0; ks < 6; ++ks) {
      bf16x8 bg[2];
#pragma unroll
      for (int j = 0; j < 2; ++j)
        bg[j] = *(bf16x8*)(&w1s[(wn * 32 + j * 16 + r16) * 200 + ks * 32 + kg * 8]);
#pragma unroll
      for (int i = 0; i < 2; ++i)
#pragma unroll
        for (int j = 0; j < 2; ++j)
          pacc[i][j] = __builtin_amdgcn_mfma_f32_16x16x32_bf16(bg[j], afr[i][ks], pacc[i][j], 0, 0, 0);
    }
    // bias + exact gelu -> h1s packed b64 writes (4 consecutive hid per lane)
#pragma unroll
    for (int i = 0; i < 2; ++i) {
      int mr = wm * 32 + i * 16 + r16;
#pragma unroll
      for (int j = 0; j < 2; ++j) {
        int hid0 = wn * 32 + j * 16 + kg * 4;
        bf16x4 pk;
#pragma unroll
        for (int t = 0; t < 4; ++t) {
          float v = pacc[i][j][t] + b1[hc * 64 + hid0 + t];
          v = 0.5f * v * (1.f + erff(v * 0.70710678118654752f));
          pk[t] = f2bf(v);
        }
        *(bf16x4*)(&h1s[mr * 72 + hid0]) = pk;
      }
    }
    __syncthreads();   // bar1: h1s ready; phase-A w1s reads done
    // w1s write-back overlaps phase B (phase B touches only h1s/w2s)
    if (hc < 11) {
#pragma unroll
      for (int it = 0; it < 6; ++it)
        *(bf16x8*)(&w1s[s1r[it] * 200 + s1c[it] * 8]) = rw1[it];
    }
    // phase B: bacc += h1s @ w2s^T
#pragma unroll
    for (int ks = 0; ks < 2; ++ks) {
      bf16x8 a2[2];
#pragma unroll
      for (int i = 0; i < 2; ++i)
        a2[i] = *(bf16x8*)(&h1s[(wm * 32 + i * 16 + r16) * 72 + ks * 32 + kg * 8]);
#pragma unroll
      for (int j = 0; j < 6; ++j) {
        bf16x8 b2g = *(bf16x8*)(&w2s[(wn * 96 + j * 16 + r16) * 72 + ks * 32 + kg * 8]);
#pragma unroll
        for (int i = 0; i < 2; ++i)
          bacc[i][j] = __builtin_amdgcn_mfma_f32_16x16x32_bf16(a2[i], b2g, bacc[i][j], 0, 0, 0);
      }
    }
    __syncthreads();   // bar2: phase-B w2s/h1s reads done; rw1 writes visible
    if (hc < 11) {     // w2s write-back; visible to next phaseB via next bar1
#pragma unroll
      for (int it = 0; it < 6; ++it)
        *(bf16x8*)(&w2s[s2r[it] * 72 + s2c[it] * 8]) = rw2[it];
    }
  }

  // epilogue: out += bacc + b2 (out holds x1 residual)
#pragma unroll
  for (int i = 0; i < 2; ++i)
#pragma unroll
    for (int j = 0; j < 6; ++j)
#pragma unroll
      for (int t = 0; t < 4; ++t) {
        int m = m0 + wm * 32 + i * 16 + kg * 4 + t;
        int n = wn * 96 + j * 16 + r16;
        size_t idx = (size_t)m * CDIM + n;
        out[idx] = bacc[i][j][t] + b2[n] + out[idx];
      }
}

extern "C" void kernel_launch(void* const* d_in, const int* in_sizes, int n_in,
                              void* d_out, int out_size, void* d_ws, size_t ws_size,
                              hipStream_t stream) {
  const float* x      = (const float*)d_in[0];
  const float* ln1_w  = (const float*)d_in[1];
  const float* ln1_b  = (const float*)d_in[2];
  const float* temp   = (const float*)d_in[3];
  const float* qkv_w  = (const float*)d_in[4];
  const float* dw_w   = (const float*)d_in[5];
  const float* proj_w = (const float*)d_in[6];
  const float* ln2_w  = (const float*)d_in[7];
  const float* ln2_b  = (const float*)d_in[8];
  const float* fc1_w  = (const float*)d_in[9];
  const float* fc1_b  = (const float*)d_in[10];
  const float* fc2_w  = (const float*)d_in[11];
  const float* fc2_b  = (const float*)d_in[12];
  float* out = (float*)d_out;

  char* base = (char*)d_ws;
  short* wq  = (short*)base;
  short* wp  = wq + 110592;
  short* w1  = wp + 36864;
  short* w2  = w1 + 147456;
  float* pdot= (float*)(base + 890880);
  float* qss = (float*)(base + 2660352);
  float* kss = (float*)(base + 2734080);
  float* atn = (float*)(base + 2807808);
  short* Dv  = (short*)(base + 4194304);         // [4][576][SSP] bf16
  short* y1t = Dv;                               // [4][SSP][192] overlay (dead before Dv)
  short* T   = (short*)(base + 230686720);       // [4][576][SSP] bf16
  short* pvt = T;                                // overlay (T dead after dwconv)
  short* y2  = (short*)(base + 457179136);       // [4][192][SSP] bf16

  // weights -> bf16
  cvt_bf16<<<dim3(432), 256, 0, stream>>>(qkv_w, wq, 110592);
  cvt_bf16<<<dim3(144), 256, 0, stream>>>(proj_w, wp, 36864);
  cvt_bf16<<<dim3(576), 256, 0, stream>>>(fc1_w, w1, 147456);
  cvt_bf16<<<dim3(576), 256, 0, stream>>>(fc2_w, w2, 147456);

  // 1. LN1 -> y1t bf16 [b][s][192] (single-read)
  ln_bf16<true><<<dim3(SSP / 64, NB), 256, 0, stream>>>(x, ln1_w, ln1_b, y1t);
  // 2. qkv GEMM (M=576,N=SSP,K=192, z=4) -> T bf16
  mfma_gemm<64, 256, 1, 4, false, true><<<dim3(SSP / 256, OC3 / 64, NB), 256, 0, stream>>>(
      wq, y1t, nullptr, T, OC3, SSP, CDIM, (long long)SSP * CDIM, (long long)OC3 * SSP);
  // 3. depthwise 3x3 tiled -> Dv bf16
  dwconv_tile<<<dim3(NB * OC3 * 8), 256, 0, stream>>>(T, dw_w, Dv);
  // 4. scores: partial dots + sumsq, then reduce+norm+softmax
  scores_stage1<<<dim3(SCCH, NHEAD, NB), 256, 0, stream>>>(Dv, pdot, qss, kss);
  scores_reduce<<<dim3(CH, NHEAD, NB), 64, 0, stream>>>(pdot, qss, kss, temp, atn);
  // 5. PV -> pvt bf16 [b][s][192]
  attn_pv_bf16<<<dim3(SSP / 256, NHEAD, NB), 256, 0, stream>>>(Dv, atn, pvt);
  // 6. x1 = proj @ pv + x -> out (fp32)
  mfma_gemm<64, 256, 1, 4, true, false><<<dim3(SSP / 256, CDIM / 64, NB), 256, 0, stream>>>(
      wp, pvt, x, out, CDIM, SSP, CDIM, (long long)SSP * CDIM, (long long)CDIM * SSP);
  // 7. LN2 -> y2 bf16 [b][c][s] (single-read)
  ln_bf16<false><<<dim3(SSP / 64, NB), 256, 0, stream>>>(out, ln2_w, ln2_b, y2);
  // 8. fused MLP v5 (64 rows/block, 2 blocks/CU)
  mlp_fused<<<dim3(196608 / 64), 256, 0, stream>>>(y2, w1, w2, fc1_b, fc2_b, out);
}

// Round 11
// 946.612 us; speedup vs baseline: 1.2703x; 1.1402x over previous
//
#include <hip/hip_runtime.h>
#include <math.h>

// TransformerBlock1: b=4, DIM=192, h=256, w=192, HEADS=8, HID=768
#define SSP   49152
#define HDIM  256
#define WDIM  192
#define CDIM  192
#define NHEAD 8
#define CH    24
#define OC3   576
#define HIDF  768
#define NB    4
#define SCCH  24

typedef short bf16x8 __attribute__((ext_vector_type(8)));
typedef short bf16x4 __attribute__((ext_vector_type(4)));
typedef float f32x4  __attribute__((ext_vector_type(4)));

__device__ inline short f2bf(float f) {
  unsigned u = __float_as_uint(f);
  u += 0x7fffu + ((u >> 16) & 1u);
  return (short)(u >> 16);
}
__device__ inline float bf2f(short h) {
  return __uint_as_float(((unsigned)(unsigned short)h) << 16);
}

// async global->LDS 16B: dest is wave-uniform base + lane*16
__device__ inline void gl_lds16(const short* g, short* l) {
  __builtin_amdgcn_global_load_lds(
      (const __attribute__((address_space(1))) unsigned int*)g,
      (__attribute__((address_space(3))) unsigned int*)l, 16, 0, 0);
}

// ---------------- f32 -> bf16 bulk convert (weights) ----------------
__global__ __launch_bounds__(256) void cvt_bf16(const float* __restrict__ in,
                                                short* __restrict__ out, int n) {
  int i = blockIdx.x * 256 + threadIdx.x;
  if (i < n) out[i] = f2bf(in[i]);
}

// ---------------- LN over channels, single global read, batched over y ----------------
template <bool TRANS>
__global__ __launch_bounds__(256) void ln_bf16(const float* __restrict__ x,
                                               const float* __restrict__ w,
                                               const float* __restrict__ bia,
                                               short* __restrict__ outp) {
  __shared__ float xs[192][68];
  __shared__ float ps[4][64], pq[4][64], mus[64], rst[64];
  const int tid = threadIdx.x;
  const int s0 = blockIdx.x * 64;
  const float* xb = x + (size_t)blockIdx.y * CDIM * SSP;
  short* outb = outp + (size_t)blockIdx.y * CDIM * SSP;
#pragma unroll
  for (int it = 0; it < 12; ++it) {
    int u = it * 256 + tid;
    int c = u >> 4, q = u & 15;
    float4 v = *(const float4*)(xb + (size_t)c * SSP + s0 + q * 4);
    *(float4*)&xs[c][q * 4] = v;
  }
  __syncthreads();
  {
    int s = tid & 63, p = tid >> 6;
    float sm = 0.f, sq = 0.f;
    for (int c = p * 48; c < p * 48 + 48; ++c) {
      float v = xs[c][s]; sm += v; sq += v * v;
    }
    ps[p][s] = sm; pq[p][s] = sq;
  }
  __syncthreads();
  if (tid < 64) {
    float sm = ps[0][tid] + ps[1][tid] + ps[2][tid] + ps[3][tid];
    float sq = pq[0][tid] + pq[1][tid] + pq[2][tid] + pq[3][tid];
    float mu = sm * (1.f / CDIM);
    mus[tid] = mu;
    rst[tid] = rsqrtf(sq * (1.f / CDIM) - mu * mu + 1e-5f);
  }
  __syncthreads();
  if (TRANS) {
#pragma unroll
    for (int it = 0; it < 6; ++it) {
      int u = it * 256 + tid;
      int c8 = u >> 6, sr = u & 63;
      float mu = mus[sr], r = rst[sr];
      bf16x8 o;
#pragma unroll
      for (int j = 0; j < 8; ++j) {
        int c = c8 * 8 + j;
        o[j] = f2bf((xs[c][sr] - mu) * r * w[c] + bia[c]);
      }
      *(bf16x8*)(outb + (size_t)(s0 + sr) * CDIM + c8 * 8) = o;
    }
  } else {
#pragma unroll
    for (int it = 0; it < 6; ++it) {
      int u = it * 256 + tid;
      int c = u >> 3, sv = u & 7;
      float wc = w[c], bc = bia[c];
      bf16x8 o;
#pragma unroll
      for (int j = 0; j < 8; ++j) {
        int s = sv * 8 + j;
        o[j] = f2bf((xs[c][s] - mus[s]) * rst[s] * wc + bc);
      }
      *(bf16x8*)(outb + (size_t)c * SSP + s0 + sv * 8) = o;
    }
  }
}

// ---------------- MFMA bf16 GEMM NT (BM=64,BN=256), global_load_lds staging ----------------
// C[m][n] = sum_k A[m][k]*B[n][k]; A shared across z, B/C/resid per z.
// Linear LDS (m97 structure): async 16B direct-to-LDS, no reg round-trip.
template <bool RESID, bool OUT_BF16>
__global__ __launch_bounds__(256) void mfma_gemm(
    const short* __restrict__ A, const short* __restrict__ B,
    const float* __restrict__ resid, void* __restrict__ Cv,
    int M, int N, int K, long long strideB, long long strideC) {
  __shared__ short As[64 * 32];     // 4 KB, linear [row][32]
  __shared__ short Bs[256 * 32];    // 16 KB, linear [row][32]
  const int tid = threadIdx.x;
  const int m0 = blockIdx.y * 64, n0 = blockIdx.x * 256;
  const long long z = blockIdx.z;
  const short* Bz = B + z * strideB;
  const int w = tid >> 6, lane = tid & 63;
  const int r16 = lane & 15, kg = lane >> 4;
  const int arow = tid >> 2, ac4 = tid & 3;   // A: chunk tid -> row, k-quarter

  f32x4 acc[4][4] = {};

  for (int k0 = 0; k0 < K; k0 += 32) {
    // A tile 64x32: 256 chunks of 16B, lane tid stages chunk tid
    gl_lds16(A + (size_t)(m0 + arow) * K + k0 + ac4 * 8, As + w * 512);
    // B tile 256x32: 1024 chunks, 4 per lane
#pragma unroll
    for (int p = 0; p < 4; ++p) {
      int flat = p * 256 + tid;
      int brow = flat >> 2, bc4 = flat & 3;
      gl_lds16(Bz + (size_t)(n0 + brow) * K + k0 + bc4 * 8, Bs + p * 2048 + w * 512);
    }
    __syncthreads();   // drains vmcnt (gload_lds) before reads
    bf16x8 af[4], bfr[4];
#pragma unroll
    for (int i = 0; i < 4; ++i)
      af[i] = *(bf16x8*)(&As[(i * 16 + r16) * 32 + kg * 8]);
#pragma unroll
    for (int j = 0; j < 4; ++j)
      bfr[j] = *(bf16x8*)(&Bs[(w * 64 + j * 16 + r16) * 32 + kg * 8]);
#pragma unroll
    for (int i = 0; i < 4; ++i)
#pragma unroll
      for (int j = 0; j < 4; ++j)
        acc[i][j] = __builtin_amdgcn_mfma_f32_16x16x32_bf16(af[i], bfr[j], acc[i][j], 0, 0, 0);
    __syncthreads();
  }

  float* Cf = (float*)Cv + z * strideC;
  short* Ch = (short*)Cv + z * strideC;
  const float* R = RESID ? resid + z * strideC : nullptr;
#pragma unroll
  for (int i = 0; i < 4; ++i) {
#pragma unroll
    for (int j = 0; j < 4; ++j) {
#pragma unroll
      for (int t = 0; t < 4; ++t) {
        int m = m0 + i * 16 + kg * 4 + t;
        int n = n0 + w * 64 + j * 16 + r16;
        float v = acc[i][j][t];
        size_t idx = (size_t)m * N + n;
        if (RESID) v += R[idx];
        if (OUT_BF16) Ch[idx] = f2bf(v); else Cf[idx] = v;
      }
    }
  }
}

// ---------------- 3x3 depthwise conv, LDS-tiled, bf16->bf16, batched ----------------
__global__ __launch_bounds__(256) void dwconv_tile(const short* __restrict__ in,
                                                   const float* __restrict__ w9,
                                                   short* __restrict__ out) {
  __shared__ short tile[34][208];
  const int tid = threadIdx.x;
  const int ch = blockIdx.x >> 3;        // b*OC3 + o
  const int slab = blockIdx.x & 7;
  const int o = ch % OC3;
  const int y0 = slab * 32;
  float wr[9];
#pragma unroll
  for (int i = 0; i < 9; ++i) wr[i] = w9[o * 9 + i];
  const short* ip = in + (size_t)ch * SSP;

  if (tid < 34) { tile[tid][7] = 0; tile[tid][200] = 0; }
#pragma unroll
  for (int i = 0; i < 4; ++i) {
    int idx = i * 256 + tid;
    if (idx < 816) {
      int row = idx / 24, cx = idx - row * 24;
      int gy = y0 + row - 1;
      bf16x8 v = {};
      if (gy >= 0 && gy < HDIM) v = *(const bf16x8*)(ip + gy * WDIM + cx * 8);
      *(bf16x8*)(&tile[row][8 + cx * 8]) = v;
    }
  }
  __syncthreads();

  short* op = out + (size_t)ch * SSP;
#pragma unroll
  for (int g = 0; g < 3; ++g) {
    int G = g * 256 + tid;
    int r = G / 24, cx = G - (G / 24) * 24;
    int cb = cx * 8 + 7;
    float a[10], b[10], c[10];
#pragma unroll
    for (int d = 0; d < 10; ++d) {
      a[d] = bf2f(tile[r][cb + d]);
      b[d] = bf2f(tile[r + 1][cb + d]);
      c[d] = bf2f(tile[r + 2][cb + d]);
    }
    bf16x8 ov;
#pragma unroll
    for (int j = 0; j < 8; ++j) {
      float acc = wr[0] * a[j] + wr[1] * a[j + 1] + wr[2] * a[j + 2]
                + wr[3] * b[j] + wr[4] * b[j + 1] + wr[5] * b[j + 2]
                + wr[6] * c[j] + wr[7] * c[j + 1] + wr[8] * c[j + 2];
      ov[j] = f2bf(acc);
    }
    *(bf16x8*)(op + (y0 + r) * WDIM + cx * 8) = ov;
  }
}

// ---------------- scores stage1: partial dots + per-row sumsq chunks (batched z) ----------------
__global__ __launch_bounds__(256) void scores_stage1(const short* __restrict__ D,
                                                     float* __restrict__ pdot,
                                                     float* __restrict__ qss,
                                                     float* __restrict__ kss) {
  int ch = blockIdx.x, h = blockIdx.y, b = blockIdx.z;
  __shared__ float qs[24][260];
  __shared__ float ks[24][260];
  int tid = threadIdx.x;
  int w = tid >> 6, lane = tid & 63;
  int c0 = w * 6;
  float acc[6] = {0.f, 0.f, 0.f, 0.f, 0.f, 0.f};
  float ssacc = 0.f;
  const short* qb = D + ((size_t)b * OC3 + h * CH) * SSP;
  const short* kb = D + ((size_t)b * OC3 + CDIM + h * CH) * SSP;
  for (int it = 0; it < 8; ++it) {
    int s0 = ch * 2048 + it * 256;
#pragma unroll
    for (int p = 0; p < 3; ++p) {
      int u = p * 256 + tid;
      int row = u >> 5, col8 = u & 31;
      bf16x8 qv = *(const bf16x8*)(qb + (size_t)row * SSP + s0 + col8 * 8);
      bf16x8 kv = *(const bf16x8*)(kb + (size_t)row * SSP + s0 + col8 * 8);
#pragma unroll
      for (int j = 0; j < 8; ++j) {
        qs[row][col8 * 8 + j] = bf2f(qv[j]);
        ks[row][col8 * 8 + j] = bf2f(kv[j]);
      }
    }
    __syncthreads();
    if (w < 2 && lane < 24) {
      const float (*src)[260] = (w == 0) ? qs : ks;
      for (int s = 0; s < 256; s += 4) {
        float4 v = *(const float4*)&src[lane][s];
        ssacc += v.x * v.x + v.y * v.y + v.z * v.z + v.w * v.w;
      }
    }
    if (lane < 24) {
      for (int s = 0; s < 256; s += 4) {
        float4 kv = *(float4*)&ks[lane][s];
#pragma unroll
        for (int i = 0; i < 6; ++i) {
          float4 qv = *(float4*)&qs[c0 + i][s];
          acc[i] += qv.x * kv.x + qv.y * kv.y + qv.z * kv.z + qv.w * kv.w;
        }
      }
    }
    __syncthreads();
  }
  if (lane < 24) {
    float* pb = pdot + (size_t)b * (NHEAD * CH * CH * SCCH);
#pragma unroll
    for (int i = 0; i < 6; ++i)
      pb[(((size_t)h * CH + (c0 + i)) * CH + lane) * SCCH + ch] = acc[i];
    if (w == 0) qss[(((size_t)b * NHEAD + h) * CH + lane) * SCCH + ch] = ssacc;
    if (w == 1) kss[(((size_t)b * NHEAD + h) * CH + lane) * SCCH + ch] = ssacc;
  }
}

// ---------------- scores reduce + norms + temperature + softmax (batched z) ----------------
__global__ void scores_reduce(const float* __restrict__ pdot,
                              const float* __restrict__ qss,
                              const float* __restrict__ kss,
                              const float* __restrict__ temp,
                              float* __restrict__ atn) {
  int c = blockIdx.x, h = blockIdx.y, b = blockIdx.z;
  int tid = threadIdx.x;   // 64
  __shared__ float row[24];
  if (tid < 24) {
    const float* p = pdot + (size_t)b * (NHEAD * CH * CH * SCCH) +
                     (((size_t)h * CH + c) * CH + tid) * SCCH;
    float s = 0.f;
#pragma unroll
    for (int i = 0; i < SCCH; ++i) s += p[i];
    const float* pq = qss + (((size_t)b * NHEAD + h) * CH + c) * SCCH;
    const float* pk = kss + (((size_t)b * NHEAD + h) * CH + tid) * SCCH;
    float sq = 0.f, sk = 0.f;
#pragma unroll
    for (int i = 0; i < SCCH; ++i) { sq += pq[i]; sk += pk[i]; }
    float rq = 1.f / fmaxf(sqrtf(sq), 1e-12f);
    float rk = 1.f / fmaxf(sqrtf(sk), 1e-12f);
    row[tid] = s * rq * rk * temp[h];
  }
  __syncthreads();
  if (tid < 24) {
    float mx = -1e30f;
    for (int d = 0; d < 24; ++d) mx = fmaxf(mx, row[d]);
    float sum = 0.f;
    for (int d = 0; d < 24; ++d) sum += expf(row[d] - mx);
    atn[((size_t)b * NHEAD + h) * 576 + c * CH + tid] = expf(row[tid] - mx) / sum;
  }
}

// ---------------- PV -> pvt bf16 [b][s][192] (batched z) ----------------
__global__ __launch_bounds__(256) void attn_pv_bf16(const short* __restrict__ D,
                                                    const float* __restrict__ atn,
                                                    short* __restrict__ pvt) {
  int nb = blockIdx.x, h = blockIdx.y, b = blockIdx.z;
  __shared__ float aL[24][24];
  int tid = threadIdx.x;
  const float* ab = atn + ((size_t)b * NHEAD + h) * 576;
  for (int i = tid; i < 576; i += 256) aL[i / 24][i % 24] = ab[i];
  __syncthreads();
  int n = nb * 256 + tid;
  const short* vb = D + ((size_t)b * OC3 + 2 * CDIM + h * CH) * SSP + n;
  float vv[24];
#pragma unroll
  for (int d = 0; d < 24; ++d) vv[d] = bf2f(vb[(size_t)d * SSP]);
  short* ob = pvt + (size_t)b * SSP * CDIM + (size_t)n * CDIM + h * CH;
  bf16x8 o0, o1, o2;
#pragma unroll
  for (int cc = 0; cc < 24; ++cc) {
    float s = 0.f;
#pragma unroll
    for (int d = 0; d < 24; ++d) s += aL[cc][d] * vv[d];
    short bv = f2bf(s);
    if (cc < 8) o0[cc & 7] = bv; else if (cc < 16) o1[cc & 7] = bv; else o2[cc & 7] = bv;
  }
  *(bf16x8*)(ob) = o0;
  *(bf16x8*)(ob + 8) = o1;
  *(bf16x8*)(ob + 16) = o2;
}

// ---------------- fused MLP v3 (round-8 config, measured 300us) ----------------
// out[m][0..191] += gelu(y2[m][:] @ w1^T + b1) @ w2^T + b2 ; 128 rows/block, 512 thr.
__global__ __launch_bounds__(512) void mlp_fused(const short* __restrict__ y2,
                                                 const short* __restrict__ w1,
                                                 const short* __restrict__ w2,
                                                 const float* __restrict__ b1,
                                                 const float* __restrict__ b2,
                                                 float* __restrict__ out) {
  __shared__ short y2s[128 * 200];   // 51200 B
  __shared__ short w1s[64 * 200];    // 25600 B
  __shared__ short w2s[192 * 72];    // 27648 B
  __shared__ short h1s[128 * 72];    // 18432 B  (total 120 KiB)
  const int tid = threadIdx.x;
  const int m0 = blockIdx.x * 128;
  const int w = tid >> 6, lane = tid & 63;
  const int r16 = lane & 15, kg = lane >> 4;
  const int wm = w >> 1, wn = w & 1;

  const int u0 = tid, u1 = 512 + tid, u2 = 1024 + tid;
  const int s1r[3] = {u0 / 24, u1 / 24, u2 / 24};
  const int s1c[3] = {u0 % 24, u1 % 24, u2 % 24};
  const int s2r[3] = {u0 / 8, u1 / 8, u2 / 8};
  const int s2c[3] = {u0 % 8, u1 % 8, u2 % 8};

  // stage y2 tile once: 128 rows x 24 vec8 chunks = 3072 -> 6 per thread
#pragma unroll
  for (int it = 0; it < 6; ++it) {
    int u = it * 512 + tid;
    int row = u / 24, cx = u % 24;
    *(bf16x8*)(&y2s[row * 200 + cx * 8]) =
        *(const bf16x8*)(y2 + (size_t)(m0 + row) * CDIM + cx * 8);
  }
  // stage chunk-0 weights
#pragma unroll
  for (int it = 0; it < 3; ++it) {
    *(bf16x8*)(&w1s[s1r[it] * 200 + s1c[it] * 8]) =
        *(const bf16x8*)(w1 + (size_t)s1r[it] * CDIM + s1c[it] * 8);
    *(bf16x8*)(&w2s[s2r[it] * 72 + s2c[it] * 8]) =
        *(const bf16x8*)(w2 + (size_t)s2r[it] * HIDF + s2c[it] * 8);
  }
  __syncthreads();

  f32x4 bacc[2][6] = {};
  bf16x8 rw1[3], rw2[3];

  for (int hc = 0; hc < 12; ++hc) {
    if (hc < 11) {     // issue next chunk's weight loads early
#pragma unroll
      for (int it = 0; it < 3; ++it) {
        rw1[it] = *(const bf16x8*)(w1 + (size_t)((hc + 1) * 64 + s1r[it]) * CDIM + s1c[it] * 8);
        rw2[it] = *(const bf16x8*)(w2 + (size_t)s2r[it] * HIDF + (hc + 1) * 64 + s2c[it] * 8);
      }
    }
    // phase A (swapped): D[hid][m]
    f32x4 pacc[2][2] = {};
#pragma unroll
    for (int ks = 0; ks < 6; ++ks) {
      bf16x8 af[2], bg[2];
#pragma unroll
      for (int i = 0; i < 2; ++i)
        af[i] = *(bf16x8*)(&y2s[(wm * 32 + i * 16 + r16) * 200 + ks * 32 + kg * 8]);
#pragma unroll
      for (int j = 0; j < 2; ++j)
        bg[j] = *(bf16x8*)(&w1s[(wn * 32 + j * 16 + r16) * 200 + ks * 32 + kg * 8]);
#pragma unroll
      for (int i = 0; i < 2; ++i)
#pragma unroll
        for (int j = 0; j < 2; ++j)
          pacc[i][j] = __builtin_amdgcn_mfma_f32_16x16x32_bf16(bg[j], af[i], pacc[i][j], 0, 0, 0);
    }
    // bias + exact gelu -> h1s packed 8B writes (4 consecutive hid per lane)
#pragma unroll
    for (int i = 0; i < 2; ++i) {
      int mr = wm * 32 + i * 16 + r16;
#pragma unroll
      for (int j = 0; j < 2; ++j) {
        int hid0 = wn * 32 + j * 16 + kg * 4;
        bf16x4 pk;
#pragma unroll
        for (int t = 0; t < 4; ++t) {
          float v = pacc[i][j][t] + b1[hc * 64 + hid0 + t];
          v = 0.5f * v * (1.f + erff(v * 0.70710678118654752f));
          pk[t] = f2bf(v);
        }
        *(bf16x4*)(&h1s[mr * 72 + hid0]) = pk;
      }
    }
    __syncthreads();   // h1s visible

    // phase B: bacc += h1s @ w2s^T
#pragma unroll
    for (int ks = 0; ks < 2; ++ks) {
      bf16x8 a2[2];
#pragma unroll
      for (int i = 0; i < 2; ++i)
        a2[i] = *(bf16x8*)(&h1s[(wm * 32 + i * 16 + r16) * 72 + ks * 32 + kg * 8]);
#pragma unroll
      for (int j = 0; j < 6; ++j) {
        bf16x8 b2g = *(bf16x8*)(&w2s[(wn * 96 + j * 16 + r16) * 72 + ks * 32 + kg * 8]);
#pragma unroll
        for (int i = 0; i < 2; ++i)
          bacc[i][j] = __builtin_amdgcn_mfma_f32_16x16x32_bf16(a2[i], b2g, bacc[i][j], 0, 0, 0);
      }
    }
    __syncthreads();   // all reads done

    // write prefetched regs -> LDS for next chunk
    if (hc < 11) {
#pragma unroll
      for (int it = 0; it < 3; ++it) {
        *(bf16x8*)(&w1s[s1r[it] * 200 + s1c[it] * 8]) = rw1[it];
        *(bf16x8*)(&w2s[s2r[it] * 72 + s2c[it] * 8]) = rw2[it];
      }
      __syncthreads();
    }
  }

  // epilogue: out += bacc + b2 (out holds x1 residual)
#pragma unroll
  for (int i = 0; i < 2; ++i)
#pragma unroll
    for (int j = 0; j < 6; ++j)
#pragma unroll
      for (int t = 0; t < 4; ++t) {
        int m = m0 + wm * 32 + i * 16 + kg * 4 + t;
        int n = wn * 96 + j * 16 + r16;
        size_t idx = (size_t)m * CDIM + n;
        out[idx] = bacc[i][j][t] + b2[n] + out[idx];
      }
}

extern "C" void kernel_launch(void* const* d_in, const int* in_sizes, int n_in,
                              void* d_out, int out_size, void* d_ws, size_t ws_size,
                              hipStream_t stream) {
  const float* x      = (const float*)d_in[0];
  const float* ln1_w  = (const float*)d_in[1];
  const float* ln1_b  = (const float*)d_in[2];
  const float* temp   = (const float*)d_in[3];
  const float* qkv_w  = (const float*)d_in[4];
  const float* dw_w   = (const float*)d_in[5];
  const float* proj_w = (const float*)d_in[6];
  const float* ln2_w  = (const float*)d_in[7];
  const float* ln2_b  = (const float*)d_in[8];
  const float* fc1_w  = (const float*)d_in[9];
  const float* fc1_b  = (const float*)d_in[10];
  const float* fc2_w  = (const float*)d_in[11];
  const float* fc2_b  = (const float*)d_in[12];
  float* out = (float*)d_out;

  char* base = (char*)d_ws;
  short* wq  = (short*)base;
  short* wp  = wq + 110592;
  short* w1  = wp + 36864;
  short* w2  = w1 + 147456;
  float* pdot= (float*)(base + 890880);
  float* qss = (float*)(base + 2660352);
  float* kss = (float*)(base + 2734080);
  float* atn = (float*)(base + 2807808);
  short* Dv  = (short*)(base + 4194304);         // [4][576][SSP] bf16
  short* y1t = Dv;                               // [4][SSP][192] overlay (dead before Dv)
  short* T   = (short*)(base + 230686720);       // [4][576][SSP] bf16
  short* pvt = T;                                // overlay (T dead after dwconv)
  short* y2  = (short*)(base + 457179136);       // [4][192][SSP] bf16

  // weights -> bf16
  cvt_bf16<<<dim3(432), 256, 0, stream>>>(qkv_w, wq, 110592);
  cvt_bf16<<<dim3(144), 256, 0, stream>>>(proj_w, wp, 36864);
  cvt_bf16<<<dim3(576), 256, 0, stream>>>(fc1_w, w1, 147456);
  cvt_bf16<<<dim3(576), 256, 0, stream>>>(fc2_w, w2, 147456);

  // 1. LN1 -> y1t bf16 [b][s][192] (single-read)
  ln_bf16<true><<<dim3(SSP / 64, NB), 256, 0, stream>>>(x, ln1_w, ln1_b, y1t);
  // 2. qkv GEMM (M=576,N=SSP,K=192, z=4) -> T bf16
  mfma_gemm<false, true><<<dim3(SSP / 256, OC3 / 64, NB), 256, 0, stream>>>(
      wq, y1t, nullptr, T, OC3, SSP, CDIM, (long long)SSP * CDIM, (long long)OC3 * SSP);
  // 3. depthwise 3x3 tiled -> Dv bf16
  dwconv_tile<<<dim3(NB * OC3 * 8), 256, 0, stream>>>(T, dw_w, Dv);
  // 4. scores: partial dots + sumsq, then reduce+norm+softmax
  scores_stage1<<<dim3(SCCH, NHEAD, NB), 256, 0, stream>>>(Dv, pdot, qss, kss);
  scores_reduce<<<dim3(CH, NHEAD, NB), 64, 0, stream>>>(pdot, qss, kss, temp, atn);
  // 5. PV -> pvt bf16 [b][s][192]
  attn_pv_bf16<<<dim3(SSP / 256, NHEAD, NB), 256, 0, stream>>>(Dv, atn, pvt);
  // 6. x1 = proj @ pv + x -> out (fp32)
  mfma_gemm<true, false><<<dim3(SSP / 256, CDIM / 64, NB), 256, 0, stream>>>(
      wp, pvt, x, out, CDIM, SSP, CDIM, (long long)SSP * CDIM, (long long)CDIM * SSP);
  // 7. LN2 -> y2 bf16 [b][c][s] (single-read)
  ln_bf16<false><<<dim3(SSP / 64, NB), 256, 0, stream>>>(out, ln2_w, ln2_b, y2);
  // 8. fused MLP v3 (round-8 config)
  mlp_fused<<<dim3(196608 / 128), 512, 0, stream>>>(y2, w1, w2, fc1_b, fc2_b, out);
}